// Round 4
// baseline (6898.650 us; speedup 1.0000x reference)
//
#include <hip/hip_runtime.h>
#include <hip/hip_fp16.h>

#define L_SEQ 2048
#define N_B   64
#define IN_K  128
#define MEM_N 256

typedef float    f32x4 __attribute__((ext_vector_type(4)));
typedef _Float16 f16x8 __attribute__((ext_vector_type(8)));

__device__ __forceinline__ float rcp_f(float x) { return __builtin_amdgcn_rcpf(x); }
__device__ __forceinline__ float tanh_f(float x) {
    return 1.0f - 2.0f * rcp_f(__expf(2.0f * x) + 1.0f);
}
__device__ __forceinline__ float sig_f(float x) {
    return rcp_f(1.0f + __expf(-x));
}

// split-f16: v ~= hi + lo with ~22-bit effective mantissa
__device__ __forceinline__ void split8(const float* v, f16x8& hi, f16x8& lo) {
#pragma unroll
    for (int i = 0; i < 8; ++i) {
        _Float16 h = (_Float16)v[i];
        hi[i] = h;
        lo[i] = (_Float16)(v[i] - (float)h);
    }
}

// 64 WGs: group g = wg&3 owns batches [16g,16g+16); slice s = wg>>2 owns rows
// [16s,16s+16). Weights live in registers (split-f16, loaded once).
// Inter-WG exchange: self-validating u64 slots {tag=t+1, payload=hf hi/lo f16}
// via RELAXED agent-scope atomics. No fences/flags/L2-maintenance.
// Serial-chain minimization: u prefetched one step ahead (latency hidden in
// post-barrier slack); hfn published before hsn/out are computed.
__global__ void __launch_bounds__(256, 1)
befrc_scan(const float* __restrict__ u,
           const float* __restrict__ Wia, const float* __restrict__ Wha,
           const float* __restrict__ Wib, const float* __restrict__ Whb,
           const float* __restrict__ Wic, const float* __restrict__ Whc,
           const float* __restrict__ Wid, const float* __restrict__ Whd,
           const float* __restrict__ Wie, const float* __restrict__ Whe,
           const float* __restrict__ Wio,
           float* __restrict__ out,                    // [64][2048][256] f32 then [64][256] f32
           unsigned long long* __restrict__ pubq)      // [2][64][256] u64 (zeroed pre-launch)
{
    const int wg  = blockIdx.x;       // 0..63
    const int g   = wg & 3;           // group 0..3
    const int s   = wg >> 2;          // m-slice 0..15
    const int tid = threadIdx.x;      // 0..255
    const int w   = tid >> 6;         // wave 0..3
    const int l   = tid & 63;
    const int lq  = l >> 4;           // 0..3
    const int lr  = l & 15;           // 0..15

    __shared__ __align__(16) float red[2][6][4][16][16]; // double-buffered, 48KB

    const float* Wi[6] = {Wia, Wib, Wic, Wid, Wie, Wio};
    const float* Wh[5] = {Wha, Whb, Whc, Whd, Whe};

    // ---- preload weight fragments into registers, split-f16 (step-invariant) ----
    const int mrow = s * 16 + lr;
    f16x8 whf_hi[5][2], whf_lo[5][2];
#pragma unroll
    for (int gg = 0; gg < 5; ++gg) {
#pragma unroll
        for (int cc = 0; cc < 2; ++cc) {
            const int k0 = (2 * w + cc) * 32 + lq * 4;
            const float* p = Wh[gg] + mrow * MEM_N + k0;
            float4 f0 = *(const float4*)p;
            float4 f1 = *(const float4*)(p + 16);
            float v[8] = {f0.x, f0.y, f0.z, f0.w, f1.x, f1.y, f1.z, f1.w};
            split8(v, whf_hi[gg][cc], whf_lo[gg][cc]);
        }
    }
    f16x8 wif_hi[6], wif_lo[6];
#pragma unroll
    for (int gg = 0; gg < 6; ++gg) {
        const int k0 = w * 32 + lq * 4;
        const float* p = Wi[gg] + mrow * IN_K + k0;
        float4 f0 = *(const float4*)p;
        float4 f1 = *(const float4*)(p + 16);
        float v[8] = {f0.x, f0.y, f0.z, f0.w, f1.x, f1.y, f1.z, f1.w};
        split8(v, wif_hi[gg], wif_lo[gg]);
    }

    // pointwise-phase element mapping: one element per thread
    const int eb    = tid >> 4;          // batch col 0..15
    const int em    = tid & 15;          // m row local 0..15
    const int bglob = g * 16 + eb;
    const int mglob = s * 16 + em;
    float hf_loc = 0.0f, hs_loc = 0.0f;

    const int  bfrag  = g * 16 + lr;                 // B-operand col = lane&15
    const long u_base = (long)bfrag * L_SEQ * IN_K + w * 32 + lq * 4;
    const int  k0a    = (2 * w + 0) * 32 + lq * 4;
    const int  k0b    = (2 * w + 1) * 32 + lq * 4;

    // ---- prologue: prefetch u(0) ----
    float4 uf0 = *(const float4*)(u + u_base);
    float4 uf1 = *(const float4*)(u + u_base + 16);

    float* const out_row = out + (long)bglob * L_SEQ * MEM_N + mglob;

    for (int t = 0; t < L_SEQ; ++t) {
        // ---- A: input projections from prefetched u (pre-spin) ----
        f32x4 acc[6];
#pragma unroll
        for (int gg = 0; gg < 6; ++gg) acc[gg] = (f32x4){0.f, 0.f, 0.f, 0.f};
        {
            float v[8] = {uf0.x, uf0.y, uf0.z, uf0.w, uf1.x, uf1.y, uf1.z, uf1.w};
            f16x8 ub_hi, ub_lo;
            split8(v, ub_hi, ub_lo);
#pragma unroll
            for (int gg = 0; gg < 6; ++gg) {
                acc[gg] = __builtin_amdgcn_mfma_f32_16x16x32_f16(wif_hi[gg], ub_hi, acc[gg], 0, 0, 0);
                acc[gg] = __builtin_amdgcn_mfma_f32_16x16x32_f16(wif_hi[gg], ub_lo, acc[gg], 0, 0, 0);
                acc[gg] = __builtin_amdgcn_mfma_f32_16x16x32_f16(wif_lo[gg], ub_hi, acc[gg], 0, 0, 0);
            }
        }

        // ---- B: per-wave spin on the 16 self-validating slots this wave consumes ----
        unsigned long long q[16];
        {
            const unsigned tgt = (unsigned)t;
            const unsigned long long* pb =
                pubq + (size_t)(t & 1) * N_B * MEM_N + (size_t)bfrag * MEM_N;
            int spins = 0;
            for (;;) {
#pragma unroll
                for (int i = 0; i < 4; ++i) {
                    q[i]      = __hip_atomic_load(pb + k0a + i,      __ATOMIC_RELAXED, __HIP_MEMORY_SCOPE_AGENT);
                    q[4 + i]  = __hip_atomic_load(pb + k0a + 16 + i, __ATOMIC_RELAXED, __HIP_MEMORY_SCOPE_AGENT);
                    q[8 + i]  = __hip_atomic_load(pb + k0b + i,      __ATOMIC_RELAXED, __HIP_MEMORY_SCOPE_AGENT);
                    q[12 + i] = __hip_atomic_load(pb + k0b + 16 + i, __ATOMIC_RELAXED, __HIP_MEMORY_SCOPE_AGENT);
                }
                int ok = 1;
#pragma unroll
                for (int i = 0; i < 16; ++i)
                    ok &= ((unsigned)(q[i] >> 32) == tgt);
                if (__all(ok) || ++spins > (1 << 18)) break;
                __builtin_amdgcn_s_sleep(1);
            }
        }

        // ---- C: unpack payloads + hidden matvecs ----
#pragma unroll
        for (int cc = 0; cc < 2; ++cc) {
            f16x8 hb_hi, hb_lo;
#pragma unroll
            for (int j = 0; j < 8; ++j) {
                const unsigned pay = (unsigned)q[cc * 8 + j];
                hb_hi[j] = __builtin_bit_cast(_Float16, (unsigned short)(pay & 0xffff));
                hb_lo[j] = __builtin_bit_cast(_Float16, (unsigned short)(pay >> 16));
            }
#pragma unroll
            for (int gg = 0; gg < 5; ++gg) {
                acc[gg] = __builtin_amdgcn_mfma_f32_16x16x32_f16(whf_hi[gg][cc], hb_hi, acc[gg], 0, 0, 0);
                acc[gg] = __builtin_amdgcn_mfma_f32_16x16x32_f16(whf_hi[gg][cc], hb_lo, acc[gg], 0, 0, 0);
                acc[gg] = __builtin_amdgcn_mfma_f32_16x16x32_f16(whf_lo[gg][cc], hb_hi, acc[gg], 0, 0, 0);
            }
        }

        // ---- D: cross-wave partial exchange (double-buffered -> single barrier) ----
        const int pb2 = t & 1;
#pragma unroll
        for (int gg = 0; gg < 6; ++gg)
            *(f32x4*)&red[pb2][gg][w][lr][lq * 4] = acc[gg];
        __syncthreads();   // (implicit vmcnt(0) drain: only old, long-drained stores)

        // ---- E: reduce partials from LDS ----
        float pre[6];
#pragma unroll
        for (int gg = 0; gg < 6; ++gg)
            pre[gg] = red[pb2][gg][0][eb][em] + red[pb2][gg][1][eb][em]
                    + red[pb2][gg][2][eb][em] + red[pb2][gg][3][eb][em];

        // ---- E2: prefetch u(t+1) — latency hidden under pointwise + next ALU ----
        {
            const long ub = u_base + (long)((t + 1 < L_SEQ) ? t + 1 : t) * IN_K;
            uf0 = *(const float4*)(u + ub);
            uf1 = *(const float4*)(u + ub + 16);
        }

        // ---- F: hfn chain first, publish immediately ----
        const float hf_old = hf_loc, hs_old = hs_loc;
        {
            const float av  = 1.0f + tanh_f(pre[0]);
            const float bv  = 1.5f * (1.0f + tanh_f(pre[1]));
            const float cv  = 0.3f  + 0.7f * sig_f(pre[2]);   // 3*DT + (1-3*DT)*sig
            const float arg = pre[5] + (av + bv * hf_old * hf_old - hs_old) * hf_old;
            hf_loc = (1.0f - cv) * hf_old + cv * tanh_f(arg);
        }
        {
            const _Float16 ph = (_Float16)hf_loc;
            const _Float16 pl = (_Float16)(hf_loc - (float)ph);
            const unsigned pay = (unsigned)__builtin_bit_cast(unsigned short, ph)
                               | ((unsigned)__builtin_bit_cast(unsigned short, pl) << 16);
            const unsigned long long val = ((unsigned long long)(unsigned)(t + 1) << 32) | pay;
            const size_t po = (size_t)((t + 1) & 1) * N_B * MEM_N
                            + (size_t)bglob * MEM_N + mglob;
            __hip_atomic_store(pubq + po, val, __ATOMIC_RELAXED, __HIP_MEMORY_SCOPE_AGENT);
        }

        // ---- G: hsn (peers don't need it) + sequence output ----
        {
            const float dv  = 0.03f * sig_f(pre[3]);          // 0.3*DT*sig
            const float ev  = 1.0f + sig_f(pre[4]);
            const float eh  = ev * hf_old;
            const float eh2 = eh * eh;
            hs_loc = hs_old * (1.0f - dv) + dv * (eh2 * eh2);
        }
        out_row[(long)t * MEM_N] = hf_loc;
    }

    // final state (second output)
    out[(long)N_B * L_SEQ * MEM_N + (long)bglob * MEM_N + mglob] = hf_loc;
}

extern "C" void kernel_launch(void* const* d_in, const int* in_sizes, int n_in,
                              void* d_out, int out_size, void* d_ws, size_t ws_size,
                              hipStream_t stream) {
    (void)in_sizes; (void)n_in; (void)out_size; (void)ws_size;
    const float* u   = (const float*)d_in[0];
    const float* Wia = (const float*)d_in[1];
    const float* Wha = (const float*)d_in[2];
    const float* Wib = (const float*)d_in[3];
    const float* Whb = (const float*)d_in[4];
    const float* Wic = (const float*)d_in[5];
    const float* Whc = (const float*)d_in[6];
    const float* Wid = (const float*)d_in[7];
    const float* Whd = (const float*)d_in[8];
    const float* Wie = (const float*)d_in[9];
    const float* Whe = (const float*)d_in[10];
    const float* Wio = (const float*)d_in[11];

    float* out = (float*)d_out;
    unsigned long long* pubq = (unsigned long long*)d_ws; // 2*64*256*8 = 262144 B

    // zero slot tags (tag 0 == step-0 expectation, payload 0 == hf0) — every
    // launch, deterministic, graph-capture safe
    hipMemsetAsync(d_ws, 0, (size_t)2 * N_B * MEM_N * sizeof(unsigned long long), stream);

    befrc_scan<<<dim3(64), dim3(256), 0, stream>>>(
        u, Wia, Wha, Wib, Whb, Wic, Whc, Wid, Whd, Wie, Whe, Wio,
        out, pubq);
}

// Round 6
// 5615.962 us; speedup vs baseline: 1.2284x; 1.2284x over previous
//
#include <hip/hip_runtime.h>
#include <hip/hip_fp16.h>

#define L_SEQ 2048
#define N_B   64
#define IN_K  128
#define MEM_N 256

typedef float    f32x4 __attribute__((ext_vector_type(4)));
typedef _Float16 f16x8 __attribute__((ext_vector_type(8)));
typedef unsigned u32x4 __attribute__((ext_vector_type(4)));

__device__ __forceinline__ float rcp_f(float x) { return __builtin_amdgcn_rcpf(x); }
__device__ __forceinline__ float tanh_f(float x) {
    return 1.0f - 2.0f * rcp_f(__expf(2.0f * x) + 1.0f);
}
__device__ __forceinline__ float sig_f(float x) {
    return rcp_f(1.0f + __expf(-x));
}

// split-f16: v ~= hi + lo with ~22-bit effective mantissa
__device__ __forceinline__ void split8(const float* v, f16x8& hi, f16x8& lo) {
#pragma unroll
    for (int i = 0; i < 8; ++i) {
        _Float16 h = (_Float16)v[i];
        hi[i] = h;
        lo[i] = (_Float16)(v[i] - (float)h);
    }
}

// 64 WGs: group g = wg&3 owns batches [16g,16g+16); slice s = wg>>2 owns rows
// [16s,16s+16). Weights live in registers (split-f16, loaded once).
// Exchange: self-validating u64 slots {tag=t+1, payload=hf hi/lo f16}.
//   produce: __hip_atomic_store RELAXED/AGENT  (proven-visible, rounds 3-4)
//   consume: asm global_load_dwordx4 sc0 sc1   (system scope >= agent: fresh)
// No fences, no flags, no L2 maintenance. One vmcnt(0) per step (in the poll);
// raw lgkm-only barrier for the cross-wave LDS reduce.
__global__ void __launch_bounds__(256, 1)
befrc_scan(const float* __restrict__ u,
           const float* __restrict__ Wia, const float* __restrict__ Wha,
           const float* __restrict__ Wib, const float* __restrict__ Whb,
           const float* __restrict__ Wic, const float* __restrict__ Whc,
           const float* __restrict__ Wid, const float* __restrict__ Whd,
           const float* __restrict__ Wie, const float* __restrict__ Whe,
           const float* __restrict__ Wio,
           float* __restrict__ out,                    // [64][2048][256] f32 then [64][256] f32
           unsigned long long* __restrict__ pubq)      // [2][64][256] u64 (zeroed pre-launch)
{
    const int wg  = blockIdx.x;       // 0..63
    const int g   = wg & 3;           // group 0..3
    const int s   = wg >> 2;          // m-slice 0..15
    const int tid = threadIdx.x;      // 0..255
    const int w   = tid >> 6;         // wave 0..3
    const int l   = tid & 63;
    const int lq  = l >> 4;           // 0..3
    const int lr  = l & 15;           // 0..15

    // [gate][wave][b(col)][m(row)] inner dim padded 16->20 floats:
    // ds_write_b128 8-way conflict -> 4-way; reads stay ~2-way. 60 KB.
    __shared__ __align__(16) float red[2][6][4][16][20];

    const float* Wi[6] = {Wia, Wib, Wic, Wid, Wie, Wio};
    const float* Wh[5] = {Wha, Whb, Whc, Whd, Whe};

    // ---- preload weight fragments into registers, split-f16 (step-invariant) ----
    const int mrow = s * 16 + lr;
    f16x8 whf_hi[5][2], whf_lo[5][2];
#pragma unroll
    for (int gg = 0; gg < 5; ++gg) {
#pragma unroll
        for (int cc = 0; cc < 2; ++cc) {
            const int k0 = (2 * w + cc) * 32 + lq * 4;
            const float* p = Wh[gg] + mrow * MEM_N + k0;
            float4 f0 = *(const float4*)p;
            float4 f1 = *(const float4*)(p + 16);
            float v[8] = {f0.x, f0.y, f0.z, f0.w, f1.x, f1.y, f1.z, f1.w};
            split8(v, whf_hi[gg][cc], whf_lo[gg][cc]);
        }
    }
    f16x8 wif_hi[6], wif_lo[6];
#pragma unroll
    for (int gg = 0; gg < 6; ++gg) {
        const int k0 = w * 32 + lq * 4;
        const float* p = Wi[gg] + mrow * IN_K + k0;
        float4 f0 = *(const float4*)p;
        float4 f1 = *(const float4*)(p + 16);
        float v[8] = {f0.x, f0.y, f0.z, f0.w, f1.x, f1.y, f1.z, f1.w};
        split8(v, wif_hi[gg], wif_lo[gg]);
    }

    // pointwise-phase element mapping: one element per thread
    const int eb    = tid >> 4;          // batch col 0..15
    const int em    = tid & 15;          // m row local 0..15
    const int bglob = g * 16 + eb;
    const int mglob = s * 16 + em;
    float hf_loc = 0.0f, hs_loc = 0.0f;

    const int  bfrag  = g * 16 + lr;                 // B-operand col = lane&15
    const long u_base = (long)bfrag * L_SEQ * IN_K + w * 32 + lq * 4;
    const int  k0a    = (2 * w + 0) * 32 + lq * 4;
    const int  k0b    = (2 * w + 1) * 32 + lq * 4;

    // prologue: issue u(0) prefetch (plain cached loads; drained by step-0 poll)
    u32x4 ua, ub2;
    {
        const float* up = u + u_base;
        asm volatile(
            "global_load_dwordx4 %0, %2, off\n\t"
            "global_load_dwordx4 %1, %3, off"
            : "=v"(ua), "=v"(ub2)
            : "v"(up), "v"(up + 16)
            : "memory");
    }

    float* const out_row = out + (long)bglob * L_SEQ * MEM_N + mglob;

#pragma clang loop unroll(disable)
    for (int t = 0; t < L_SEQ; ++t) {
        // ---- B: poll the 16 self-validating slots this wave consumes.
        // One asm block: 8x dwordx4 (sc0 sc1 = system scope) + vmcnt(0).
        // The vmcnt(0) also retires the older u-prefetch / pub / out ops
        // (issued >=1200cy ago -> free), making this the loop's only VMEM wait.
        u32x4 r0, r1, r2, r3, r4, r5, r6, r7;
        {
            const unsigned tgt = (unsigned)t;
            const unsigned long long* pb =
                pubq + (size_t)(t & 1) * N_B * MEM_N + (size_t)bfrag * MEM_N;
            const unsigned long long* p0 = pb + k0a;
            const unsigned long long* p1 = pb + k0a + 16;
            const unsigned long long* p2 = pb + k0b;
            const unsigned long long* p3 = pb + k0b + 16;
            int spins = 0;
            for (;;) {
                asm volatile(
                    "global_load_dwordx4 %0, %8, off sc0 sc1\n\t"
                    "global_load_dwordx4 %1, %8, off offset:16 sc0 sc1\n\t"
                    "global_load_dwordx4 %2, %9, off sc0 sc1\n\t"
                    "global_load_dwordx4 %3, %9, off offset:16 sc0 sc1\n\t"
                    "global_load_dwordx4 %4, %10, off sc0 sc1\n\t"
                    "global_load_dwordx4 %5, %10, off offset:16 sc0 sc1\n\t"
                    "global_load_dwordx4 %6, %11, off sc0 sc1\n\t"
                    "global_load_dwordx4 %7, %11, off offset:16 sc0 sc1\n\t"
                    "s_waitcnt vmcnt(0)"
                    : "=v"(r0), "=v"(r1), "=v"(r2), "=v"(r3),
                      "=v"(r4), "=v"(r5), "=v"(r6), "=v"(r7)
                    : "v"(p0), "v"(p1), "v"(p2), "v"(p3)
                    : "memory");
                int ok = (r0[1] == tgt) & (r0[3] == tgt) & (r1[1] == tgt) & (r1[3] == tgt)
                       & (r2[1] == tgt) & (r2[3] == tgt) & (r3[1] == tgt) & (r3[3] == tgt)
                       & (r4[1] == tgt) & (r4[3] == tgt) & (r5[1] == tgt) & (r5[3] == tgt)
                       & (r6[1] == tgt) & (r6[3] == tgt) & (r7[1] == tgt) & (r7[3] == tgt);
                if (__all(ok) || ++spins > (1 << 17)) break;
            }
        }
        // fence: nothing below (esp. split8 of ua/ub2, asm-defined last iter)
        // may be hoisted above the poll's vmcnt(0)  [rule 18]
        __builtin_amdgcn_sched_barrier(0);

        // ---- A: input projections from prefetched u ----
        f32x4 acc[6];
#pragma unroll
        for (int gg = 0; gg < 6; ++gg) acc[gg] = (f32x4){0.f, 0.f, 0.f, 0.f};
        {
            float4 f0 = __builtin_bit_cast(float4, ua);
            float4 f1 = __builtin_bit_cast(float4, ub2);
            float v[8] = {f0.x, f0.y, f0.z, f0.w, f1.x, f1.y, f1.z, f1.w};
            f16x8 uh, ul;
            split8(v, uh, ul);
#pragma unroll
            for (int gg = 0; gg < 6; ++gg) {
                acc[gg] = __builtin_amdgcn_mfma_f32_16x16x32_f16(wif_hi[gg], uh, acc[gg], 0, 0, 0);
                acc[gg] = __builtin_amdgcn_mfma_f32_16x16x32_f16(wif_hi[gg], ul, acc[gg], 0, 0, 0);
                acc[gg] = __builtin_amdgcn_mfma_f32_16x16x32_f16(wif_lo[gg], uh, acc[gg], 0, 0, 0);
            }
        }

        // ---- B2: issue u(t+1) prefetch (no wait; retired by next step's poll) ----
        {
            const float* up = u + u_base + (long)((t + 1 < L_SEQ) ? t + 1 : t) * IN_K;
            asm volatile(
                "global_load_dwordx4 %0, %2, off\n\t"
                "global_load_dwordx4 %1, %3, off"
                : "=v"(ua), "=v"(ub2)
                : "v"(up), "v"(up + 16)
                : "memory");
        }

        // ---- C: unpack payloads + hidden matvecs ----
        unsigned pay[16] = {r0[0], r0[2], r1[0], r1[2], r2[0], r2[2], r3[0], r3[2],
                            r4[0], r4[2], r5[0], r5[2], r6[0], r6[2], r7[0], r7[2]};
#pragma unroll
        for (int cc = 0; cc < 2; ++cc) {
            f16x8 hb_hi, hb_lo;
#pragma unroll
            for (int j = 0; j < 8; ++j) {
                const unsigned p = pay[cc * 8 + j];
                hb_hi[j] = __builtin_bit_cast(_Float16, (unsigned short)(p & 0xffff));
                hb_lo[j] = __builtin_bit_cast(_Float16, (unsigned short)(p >> 16));
            }
#pragma unroll
            for (int gg = 0; gg < 5; ++gg) {
                acc[gg] = __builtin_amdgcn_mfma_f32_16x16x32_f16(whf_hi[gg][cc], hb_hi, acc[gg], 0, 0, 0);
                acc[gg] = __builtin_amdgcn_mfma_f32_16x16x32_f16(whf_hi[gg][cc], hb_lo, acc[gg], 0, 0, 0);
                acc[gg] = __builtin_amdgcn_mfma_f32_16x16x32_f16(whf_lo[gg][cc], hb_hi, acc[gg], 0, 0, 0);
            }
        }

        // ---- D: cross-wave partial exchange; raw lgkm-only barrier (no vmcnt drain) ----
        const int pb2 = t & 1;
#pragma unroll
        for (int gg = 0; gg < 6; ++gg)
            *(f32x4*)&red[pb2][gg][w][lr][lq * 4] = acc[gg];
        asm volatile("s_waitcnt lgkmcnt(0)\n\ts_barrier" ::: "memory");
        __builtin_amdgcn_sched_barrier(0);

        // ---- E: reduce hfn-relevant gates {a,b,c,o} first; publish early ----
        float pre0, pre1, pre2, pre5;
        pre0 = red[pb2][0][0][eb][em] + red[pb2][0][1][eb][em]
             + red[pb2][0][2][eb][em] + red[pb2][0][3][eb][em];
        pre1 = red[pb2][1][0][eb][em] + red[pb2][1][1][eb][em]
             + red[pb2][1][2][eb][em] + red[pb2][1][3][eb][em];
        pre2 = red[pb2][2][0][eb][em] + red[pb2][2][1][eb][em]
             + red[pb2][2][2][eb][em] + red[pb2][2][3][eb][em];
        pre5 = red[pb2][5][0][eb][em] + red[pb2][5][1][eb][em]
             + red[pb2][5][2][eb][em] + red[pb2][5][3][eb][em];

        const float hf_old = hf_loc, hs_old = hs_loc;
        {
            const float av  = 1.0f + tanh_f(pre0);
            const float bv  = 1.5f * (1.0f + tanh_f(pre1));
            const float cv  = 0.3f  + 0.7f * sig_f(pre2);     // 3*DT + (1-3*DT)*sig
            const float arg = pre5 + (av + bv * hf_old * hf_old - hs_old) * hf_old;
            hf_loc = (1.0f - cv) * hf_old + cv * tanh_f(arg);
        }
        {
            const _Float16 ph = (_Float16)hf_loc;
            const _Float16 pl = (_Float16)(hf_loc - (float)ph);
            const unsigned paw = (unsigned)__builtin_bit_cast(unsigned short, ph)
                               | ((unsigned)__builtin_bit_cast(unsigned short, pl) << 16);
            const unsigned long long val = ((unsigned long long)(unsigned)(t + 1) << 32) | paw;
            const size_t po = (size_t)((t + 1) & 1) * N_B * MEM_N
                            + (size_t)bglob * MEM_N + mglob;
            __hip_atomic_store(pubq + po, val, __ATOMIC_RELAXED, __HIP_MEMORY_SCOPE_AGENT);
        }

        // ---- G: hsn (peers don't need it) + sequence output ----
        {
            const float pre3 = red[pb2][3][0][eb][em] + red[pb2][3][1][eb][em]
                             + red[pb2][3][2][eb][em] + red[pb2][3][3][eb][em];
            const float pre4 = red[pb2][4][0][eb][em] + red[pb2][4][1][eb][em]
                             + red[pb2][4][2][eb][em] + red[pb2][4][3][eb][em];
            const float dv  = 0.03f * sig_f(pre3);            // 0.3*DT*sig
            const float ev  = 1.0f + sig_f(pre4);
            const float eh  = ev * hf_old;
            const float eh2 = eh * eh;
            hs_loc = hs_old * (1.0f - dv) + dv * (eh2 * eh2);
        }
        out_row[(long)t * MEM_N] = hf_loc;
    }

    // final state (second output)
    out[(long)N_B * L_SEQ * MEM_N + (long)bglob * MEM_N + mglob] = hf_loc;
}

extern "C" void kernel_launch(void* const* d_in, const int* in_sizes, int n_in,
                              void* d_out, int out_size, void* d_ws, size_t ws_size,
                              hipStream_t stream) {
    (void)in_sizes; (void)n_in; (void)out_size; (void)ws_size;
    const float* u   = (const float*)d_in[0];
    const float* Wia = (const float*)d_in[1];
    const float* Wha = (const float*)d_in[2];
    const float* Wib = (const float*)d_in[3];
    const float* Whb = (const float*)d_in[4];
    const float* Wic = (const float*)d_in[5];
    const float* Whc = (const float*)d_in[6];
    const float* Wid = (const float*)d_in[7];
    const float* Whd = (const float*)d_in[8];
    const float* Wie = (const float*)d_in[9];
    const float* Whe = (const float*)d_in[10];
    const float* Wio = (const float*)d_in[11];

    float* out = (float*)d_out;
    unsigned long long* pubq = (unsigned long long*)d_ws; // 2*64*256*8 = 262144 B

    // zero slot tags (tag 0 == step-0 expectation, payload 0 == hf0) — every
    // launch, deterministic, graph-capture safe
    hipMemsetAsync(d_ws, 0, (size_t)2 * N_B * MEM_N * sizeof(unsigned long long), stream);

    befrc_scan<<<dim3(64), dim3(256), 0, stream>>>(
        u, Wia, Wha, Wib, Whb, Wic, Whc, Wid, Whd, Wie, Whe, Wio,
        out, pubq);
}